// Round 2
// baseline (463.708 us; speedup 1.0000x reference)
//
#include <hip/hip_runtime.h>

// TimeGraphNet [64,1024,1200] f32 -> softmax [64,3].
//
// Structure (R1): barrier-free streaming.
//  K1 conv1_pool1: 3 threads per row, each owns 400 contiguous floats
//     (50 conv1 outputs = 10 pool1 windows). Aligned float4 loads,
//     double-buffered per window; all conv/pool in registers.
//     Writes p1[row][32-padded] (30 valid) to ws.
//  K2 tail: 1 thread per row: conv2(K3,s3) -> maxpool(3,3,pad1,-inf)
//     -> conv3(K4) -> relu -> feat[row].
//  K3 classifier: 64 blocks, 3 dot-1024 + softmax.
//
// Per-row math (verified exact in R0):
//  y1[j] = relu(b1 + sum_k w1[k]*x[8j-1+k]), j=0..149, zero pad at -1,1200
//  p1[m] = max(y1[5m..5m+4])
//  y2[j] = relu(b2 + sum_k w2[k]*p1[3j+k]), j=0..9
//  p2 = {max(y2[0],y2[1]), max(y2[2..4]), max(y2[5..7]), max(y2[8],y2[9])}
//  feat = relu(b3 + dot(w3, p2))

#define NROWS 65536
#define P1_STRIDE 32

__global__ __launch_bounds__(256, 3) void conv1_pool1_kernel(
    const float* __restrict__ input,
    const float* __restrict__ w1g, const float* __restrict__ b1g,
    float* __restrict__ p1out)
{
    const int t = blockIdx.x * 256 + threadIdx.x;   // 0 .. 196607
    const int row = t / 3;
    const int s = t - row * 3;                      // segment 0..2
    const float* rowp = input + (size_t)row * 1200 + s * 400;
    const float4* rp4 = (const float4*)rowp;        // 400-float seg, 16B aligned

    float w1[10];
    #pragma unroll
    for (int k = 0; k < 10; ++k) w1[k] = w1g[k];
    const float b1 = b1g[0];

    // carry = x[seg_base - 1] (zero pad at row start)
    float carry = (s == 0) ? 0.0f : rowp[-1];

    float4 cur[10], nxt[10];
    #pragma unroll
    for (int q = 0; q < 10; ++q) cur[q] = rp4[q];

    float* out = p1out + (size_t)row * P1_STRIDE + s * 10;

    #pragma unroll 1
    for (int w = 0; w < 10; ++w) {
        float la;  // lookahead = x[seg_base + 40w + 40]
        if (w < 9) {
            #pragma unroll
            for (int q = 0; q < 10; ++q) nxt[q] = rp4[(w + 1) * 10 + q];
            la = nxt[0].x;
        } else {
            // last window of the segment: next float is x[400(s+1)];
            // for s==2 that's x[1200] -> zero pad.
            la = (s < 2) ? rowp[400] : 0.0f;
        }

        const float* f = (const float*)cur;  // f[n] = x[seg+40w+n], const idx
        float pmax = 0.0f;                   // relu floor folded into pool
        #pragma unroll
        for (int i = 0; i < 5; ++i) {
            const float x_m1 = (i == 0) ? carry : f[8 * i - 1];
            const float x_p8 = (i == 4) ? la : f[8 * i + 8];
            float acc = b1;
            acc = fmaf(w1[0], x_m1, acc);
            #pragma unroll
            for (int k = 1; k <= 8; ++k) acc = fmaf(w1[k], f[8 * i - 1 + k], acc);
            acc = fmaf(w1[9], x_p8, acc);
            pmax = fmaxf(pmax, acc);
        }
        out[w] = pmax;

        carry = f[39];
        #pragma unroll
        for (int q = 0; q < 10; ++q) cur[q] = nxt[q];
    }
}

__global__ __launch_bounds__(256) void tail_kernel(
    const float* __restrict__ p1,
    const float* __restrict__ w2g, const float* __restrict__ b2g,
    const float* __restrict__ w3g, const float* __restrict__ b3g,
    float* __restrict__ feat)
{
    const int row = blockIdx.x * 256 + threadIdx.x;
    const float* p = p1 + (size_t)row * P1_STRIDE;

    const float w2a = w2g[0], w2b = w2g[1], w2c = w2g[2];
    const float b2 = b2g[0];

    float y2[10];
    #pragma unroll
    for (int j = 0; j < 10; ++j) {
        float acc = b2;
        acc = fmaf(w2a, p[3 * j], acc);
        acc = fmaf(w2b, p[3 * j + 1], acc);
        acc = fmaf(w2c, p[3 * j + 2], acc);
        y2[j] = fmaxf(acc, 0.0f);
    }
    const float q0 = fmaxf(y2[0], y2[1]);
    const float q1 = fmaxf(fmaxf(y2[2], y2[3]), y2[4]);
    const float q2 = fmaxf(fmaxf(y2[5], y2[6]), y2[7]);
    const float q3 = fmaxf(y2[8], y2[9]);

    float f = b3g[0];
    f = fmaf(w3g[0], q0, f);
    f = fmaf(w3g[1], q1, f);
    f = fmaf(w3g[2], q2, f);
    f = fmaf(w3g[3], q3, f);
    feat[row] = fmaxf(f, 0.0f);
}

__global__ __launch_bounds__(256) void classifier_kernel(
    const float* __restrict__ feat,
    const float* __restrict__ cls_w,
    const float* __restrict__ cls_b,
    float* __restrict__ out)
{
    const int b = blockIdx.x;
    const int tid = threadIdx.x;

    float s0 = 0.0f, s1 = 0.0f, s2 = 0.0f;
    for (int n = tid; n < 1024; n += 256) {
        const float f = feat[b * 1024 + n];
        s0 = fmaf(f, cls_w[n], s0);
        s1 = fmaf(f, cls_w[1024 + n], s1);
        s2 = fmaf(f, cls_w[2048 + n], s2);
    }
    #pragma unroll
    for (int off = 32; off > 0; off >>= 1) {
        s0 += __shfl_down(s0, off, 64);
        s1 += __shfl_down(s1, off, 64);
        s2 += __shfl_down(s2, off, 64);
    }
    __shared__ float red[3][4];
    const int wave = tid >> 6;
    if ((tid & 63) == 0) {
        red[0][wave] = s0;
        red[1][wave] = s1;
        red[2][wave] = s2;
    }
    __syncthreads();
    if (tid == 0) {
        const float l0 = red[0][0] + red[0][1] + red[0][2] + red[0][3] + cls_b[0];
        const float l1 = red[1][0] + red[1][1] + red[1][2] + red[1][3] + cls_b[1];
        const float l2 = red[2][0] + red[2][1] + red[2][2] + red[2][3] + cls_b[2];
        const float m = fmaxf(l0, fmaxf(l1, l2));
        const float e0 = expf(l0 - m);
        const float e1 = expf(l1 - m);
        const float e2 = expf(l2 - m);
        const float inv = 1.0f / (e0 + e1 + e2);
        out[b * 3 + 0] = e0 * inv;
        out[b * 3 + 1] = e1 * inv;
        out[b * 3 + 2] = e2 * inv;
    }
}

extern "C" void kernel_launch(void* const* d_in, const int* in_sizes, int n_in,
                              void* d_out, int out_size, void* d_ws, size_t ws_size,
                              hipStream_t stream) {
    const float* input   = (const float*)d_in[0];
    const float* conv1_w = (const float*)d_in[1];
    const float* conv1_b = (const float*)d_in[2];
    const float* conv2_w = (const float*)d_in[3];
    const float* conv2_b = (const float*)d_in[4];
    const float* conv3_w = (const float*)d_in[5];
    const float* conv3_b = (const float*)d_in[6];
    // d_in[7..10]: gcn params — dead code in the reference.
    const float* cls_w   = (const float*)d_in[11];
    const float* cls_b   = (const float*)d_in[12];

    float* wsf  = (float*)d_ws;
    float* feat = wsf;                    // 65536 floats (256 KB)
    float* p1   = wsf + NROWS;            // 65536*32 floats (8 MB)
    float* out  = (float*)d_out;

    conv1_pool1_kernel<<<(NROWS * 3) / 256, 256, 0, stream>>>(
        input, conv1_w, conv1_b, p1);
    tail_kernel<<<NROWS / 256, 256, 0, stream>>>(
        p1, conv2_w, conv2_b, conv3_w, conv3_b, feat);
    classifier_kernel<<<64, 256, 0, stream>>>(feat, cls_w, cls_b, out);
}

// Round 3
// 424.580 us; speedup vs baseline: 1.0922x; 1.0922x over previous
//
#include <hip/hip_runtime.h>

// TimeGraphNet [64,1024,1200] f32 -> softmax [64,3].
//
// R2 structure: single fused kernel (8 rows/block, LDS-staged, coalesced)
// computes conv1->pool1->conv2->pool2->conv3->relu->per-row classifier
// product, emitting 3 partial logits per block; a tiny deterministic
// reduction+softmax kernel finishes. No intermediate global traffic.
//
// Per-row math (verified exact in R0/R1):
//  y1[j] = relu(b1 + sum_{k=0..9} w1[k]*x[8j-1+k]), j=0..149, zero pad
//  p1[m] = max(y1[5m..5m+4])                                  (30 vals)
//  y2[j] = relu(b2 + sum_{k=0..2} w2[k]*p1[3j+k]), j=0..9
//  p2 = {max(y2[0],y2[1]), max(y2[2..4]), max(y2[5..7]), max(y2[8],y2[9])}
//  feat = relu(b3 + dot(w3, p2))
//  logits[b,c] = sum_n feat[b,n]*cls_w[c,n] + cls_b[c]; softmax over c.

#define ROWS_PER_BLOCK 8
#define STRIDE_F 1220          // LDS row stride in floats (1200+20; ≡4 mod 32)
#define STRIDE_F4 305
#define NBLOCKS 8192           // 65536 rows / 8

__global__ __launch_bounds__(256) void fused_chain_kernel(
    const float* __restrict__ input,
    const float* __restrict__ w1g, const float* __restrict__ b1g,
    const float* __restrict__ w2g, const float* __restrict__ b2g,
    const float* __restrict__ w3g, const float* __restrict__ b3g,
    const float* __restrict__ cls_w,
    float* __restrict__ partials)
{
    __shared__ __align__(16) float xs[ROWS_PER_BLOCK * STRIDE_F]; // 39040 B
    __shared__ float p1s[ROWS_PER_BLOCK][30];
    __shared__ float pl[ROWS_PER_BLOCK][3];

    const int tid = threadIdx.x;
    const int blk = blockIdx.x;

    // Stage 8 contiguous rows (9600 floats = 2400 float4), coalesced.
    const float4* src = (const float4*)(input + (size_t)blk * 9600);
    #pragma unroll
    for (int it = 0; it < 10; ++it) {
        const int i = tid + it * 256;
        if (i < 2400) {
            const float4 vv = src[i];
            const int r = i / 300;
            const int c4 = i - r * 300;
            ((float4*)xs)[r * STRIDE_F4 + c4] = vv;
        }
    }

    float w1[10];
    #pragma unroll
    for (int k = 0; k < 10; ++k) w1[k] = w1g[k];
    const float b1 = b1g[0];

    __syncthreads();

    // 240 tasks: (row r = tid&7, pool-window w = tid>>3).
    // Window w needs x[40w-1 .. 40w+40] (42 values, zero pad at edges).
    if (tid < 240) {
        const int r = tid & 7;
        const int w = tid >> 3;
        const float* xr = xs + r * STRIDE_F + w * 40;
        float v[42];
        v[0] = (w == 0) ? 0.0f : xr[-1];
        #pragma unroll
        for (int m = 1; m <= 40; ++m) v[m] = xr[m - 1];
        v[41] = (w == 29) ? 0.0f : xr[40];

        float pmax = 0.0f;  // relu folded into pool (outputs >= 0)
        #pragma unroll
        for (int i = 0; i < 5; ++i) {
            float acc = b1;
            #pragma unroll
            for (int k = 0; k < 10; ++k) acc = fmaf(w1[k], v[8 * i + k], acc);
            pmax = fmaxf(pmax, acc);
        }
        p1s[r][w] = pmax;
    }
    __syncthreads();

    // Per-row tail + classifier product: 8 threads.
    if (tid < 8) {
        const float* p = p1s[tid];
        const float w2a = w2g[0], w2b = w2g[1], w2c = w2g[2], b2 = b2g[0];
        float y2[10];
        #pragma unroll
        for (int j = 0; j < 10; ++j) {
            float acc = fmaf(w2c, p[3 * j + 2],
                        fmaf(w2b, p[3 * j + 1],
                        fmaf(w2a, p[3 * j], b2)));
            y2[j] = fmaxf(acc, 0.0f);
        }
        const float q0 = fmaxf(y2[0], y2[1]);
        const float q1 = fmaxf(fmaxf(y2[2], y2[3]), y2[4]);
        const float q2 = fmaxf(fmaxf(y2[5], y2[6]), y2[7]);
        const float q3 = fmaxf(y2[8], y2[9]);
        float f = b3g[0];
        f = fmaf(w3g[0], q0, f);
        f = fmaf(w3g[1], q1, f);
        f = fmaf(w3g[2], q2, f);
        f = fmaf(w3g[3], q3, f);
        f = fmaxf(f, 0.0f);
        const int n = ((blk & 127) << 3) + tid;   // row index within batch
        pl[tid][0] = f * cls_w[n];
        pl[tid][1] = f * cls_w[1024 + n];
        pl[tid][2] = f * cls_w[2048 + n];
    }
    __syncthreads();

    if (tid < 3) {
        float s = 0.0f;
        #pragma unroll
        for (int r = 0; r < 8; ++r) s += pl[r][tid];
        partials[blk * 3 + tid] = s;
    }
}

// 64 blocks (one per batch), 128 threads: sum 128 blocks' partials,
// add bias, softmax over 3 classes. Deterministic reduction.
__global__ __launch_bounds__(128) void reduce_softmax_kernel(
    const float* __restrict__ partials,
    const float* __restrict__ cls_b,
    float* __restrict__ out)
{
    const int b = blockIdx.x;
    const int t = threadIdx.x;
    const float* p = partials + (size_t)b * 128 * 3 + t * 3;
    float s0 = p[0], s1 = p[1], s2 = p[2];
    #pragma unroll
    for (int off = 32; off > 0; off >>= 1) {
        s0 += __shfl_down(s0, off, 64);
        s1 += __shfl_down(s1, off, 64);
        s2 += __shfl_down(s2, off, 64);
    }
    __shared__ float red[3][2];
    if ((t & 63) == 0) {
        const int w = t >> 6;
        red[0][w] = s0;
        red[1][w] = s1;
        red[2][w] = s2;
    }
    __syncthreads();
    if (t == 0) {
        const float l0 = red[0][0] + red[0][1] + cls_b[0];
        const float l1 = red[1][0] + red[1][1] + cls_b[1];
        const float l2 = red[2][0] + red[2][1] + cls_b[2];
        const float m = fmaxf(l0, fmaxf(l1, l2));
        const float e0 = expf(l0 - m);
        const float e1 = expf(l1 - m);
        const float e2 = expf(l2 - m);
        const float inv = 1.0f / (e0 + e1 + e2);
        out[b * 3 + 0] = e0 * inv;
        out[b * 3 + 1] = e1 * inv;
        out[b * 3 + 2] = e2 * inv;
    }
}

extern "C" void kernel_launch(void* const* d_in, const int* in_sizes, int n_in,
                              void* d_out, int out_size, void* d_ws, size_t ws_size,
                              hipStream_t stream) {
    const float* input   = (const float*)d_in[0];
    const float* conv1_w = (const float*)d_in[1];
    const float* conv1_b = (const float*)d_in[2];
    const float* conv2_w = (const float*)d_in[3];
    const float* conv2_b = (const float*)d_in[4];
    const float* conv3_w = (const float*)d_in[5];
    const float* conv3_b = (const float*)d_in[6];
    // d_in[7..10]: gcn params — dead code in the reference.
    const float* cls_w   = (const float*)d_in[11];
    const float* cls_b   = (const float*)d_in[12];

    float* partials = (float*)d_ws;       // 8192*3 floats = 96 KB
    float* out      = (float*)d_out;      // 64*3 fp32

    fused_chain_kernel<<<NBLOCKS, 256, 0, stream>>>(
        input, conv1_w, conv1_b, conv2_w, conv2_b, conv3_w, conv3_b,
        cls_w, partials);
    reduce_softmax_kernel<<<64, 128, 0, stream>>>(partials, cls_b, out);
}